// Round 1
// 884.503 us; speedup vs baseline: 1.6478x; 1.6478x over previous
//
#include <hip/hip_runtime.h>

typedef _Float16 f16;
typedef _Float16 f16x2 __attribute__((ext_vector_type(2)));
typedef _Float16 f16x4 __attribute__((ext_vector_type(4)));
typedef _Float16 f16x8 __attribute__((ext_vector_type(8)));
typedef float f32x4 __attribute__((ext_vector_type(4)));

constexpr int TQn = 1024, TKn = 1024, Dn = 64, Bn = 32;
constexpr int NB = 8;     // batches per block
constexpr int NQ = 16;    // queries per block
constexpr int KT = 32;    // k-tile
constexpr int NSTEP = TKn / KT;   // 32

// ---- LDS byte layout ----
constexpr int KROW  = 136;                 // 68 f16 per k-row (64 + 4 pad) -> conflict-free B-frag reads
constexpr int KTILE = KT * KROW;           // 4352 B per b (or q)
constexpr int LK    = 0;                   // K tiles:  NB*KTILE = 34816
constexpr int LPK   = NB * KTILE;          // PK tiles: NQ*KTILE = 69632  (end 104448)
constexpr int VTROW = 72;                  // 36 f16 per d-row (32 + 4 pad)
constexpr int VTILE = Dn * VTROW;          // 4608 B per b (or q)
constexpr int LVT   = 0;                   // V^T:  NB*VTILE = 36864   (aliases K region)
constexpr int LPVT  = NB * VTILE;          // PV^T: NQ*VTILE = 73728   (end 110592)
constexpr int OPS   = LPVT + NQ * VTILE;   // 110592 shared operand union
constexpr int LS    = OPS;                 // S: 128 rows * 136 B (34 f32, padded); P f16 aliased in-row
constexpr int SROWF = 34;
constexpr int LMo   = LS + 128 * 136;      // 128000: running max, 128 f32
constexpr int LLo   = LMo + 512;           // running sum
constexpr int LAo   = LLo + 512;           // per-step alpha
constexpr int LVLq  = LAo + 512;           // valid_lens, 8 ints
constexpr int SMEMB = LVLq + 32;           // 129568 B (<160K, 1 block/CU)
constexpr int OROWF = 68;                  // epilogue pos-O row stride (floats), in ops region

union F4 { float4 v; float a[4]; };

__device__ __forceinline__ f16x8 ld8(const void* p) {   // 8-aligned LDS f16x8 load (2x b64)
  f16x4 a = *(const f16x4*)p;
  f16x4 b = *(const f16x4*)((const char*)p + 8);
  return __builtin_shufflevector(a, b, 0, 1, 2, 3, 4, 5, 6, 7);
}
__device__ __forceinline__ f16x4 cvt4(float4 x) {
  f16x4 r; r[0] = (f16)x.x; r[1] = (f16)x.y; r[2] = (f16)x.z; r[3] = (f16)x.w;
  return r;
}

// MFMA 16x16x32 f16 layouts (gfx950):
//  A: row = lane&15, k = (lane>>4)*8 + j   (8 f16)
//  B: col = lane&15, k = (lane>>4)*8 + j
//  C/D: col = lane&15, row = (lane>>4)*4 + reg   [verified layout]
__global__ __launch_bounds__(512, 2)
void attn_rpr_mfma(const float* __restrict__ Qg, const float* __restrict__ Kg,
                   const float* __restrict__ Vg, const float* __restrict__ PKg,
                   const float* __restrict__ PVg, const int* __restrict__ VLg,
                   float* __restrict__ Og) {
  __shared__ __align__(16) char sm[SMEMB];
  float* const sM  = (float*)(sm + LMo);
  float* const sL  = (float*)(sm + LLo);
  float* const sA  = (float*)(sm + LAo);
  int*   const sVL = (int*)(sm + LVLq);
  float* const sS  = (float*)(sm + LS);

  const int tid = (int)threadIdx.x;
  const int w = tid >> 6, l = tid & 63;
  const int l16 = l & 15, g = l >> 4;
  const int qt = (int)blockIdx.x, bg = (int)blockIdx.y;
  const int q0 = qt * NQ, b0 = bg * NB;

  if (tid < 128) { sM[tid] = -3.0e38f; sL[tid] = 0.0f; }
  if (tid < NB) sVL[tid] = VLg[b0 + tid];

  // ---- persistent Q fragments ----
  // content (wave w owns b=w): A rows = 16 q's; pos (wave w owns q=2w,2w+1): A rows = b (8 real, 8 zero)
  f16x8 aQc[2], aQp[2][2];
  {
    const float* qr = Qg + ((size_t)(b0 + w) * TQn + (q0 + l16)) * Dn;
#pragma unroll
    for (int c = 0; c < 2; ++c) {
      float4 x = *(const float4*)(qr + c * 32 + g * 8);
      float4 y = *(const float4*)(qr + c * 32 + g * 8 + 4);
      aQc[c] = __builtin_shufflevector(cvt4(x), cvt4(y), 0, 1, 2, 3, 4, 5, 6, 7);
    }
    const int bp = l16 & 7;
    const bool vld = (l16 < 8);
#pragma unroll
    for (int qi = 0; qi < 2; ++qi) {
      const float* qp = Qg + ((size_t)(b0 + bp) * TQn + (q0 + 2 * w + qi)) * Dn;
#pragma unroll
      for (int c = 0; c < 2; ++c) {
        float4 x = *(const float4*)(qp + c * 32 + g * 8);
        float4 y = *(const float4*)(qp + c * 32 + g * 8 + 4);
        if (!vld) { x = make_float4(0.f, 0.f, 0.f, 0.f); y = make_float4(0.f, 0.f, 0.f, 0.f); }
        aQp[qi][c] = __builtin_shufflevector(cvt4(x), cvt4(y), 0, 1, 2, 3, 4, 5, 6, 7);
      }
    }
  }
  __syncthreads();

  int vmax = 0;
#pragma unroll
  for (int i = 0; i < NB; ++i) vmax = max(vmax, sVL[i]);

  const f32x4 z4 = {0.f, 0.f, 0.f, 0.f};
  f32x4 Oc[4], Op[2][4];
#pragma unroll
  for (int n = 0; n < 4; ++n) { Oc[n] = z4; Op[0][n] = z4; Op[1][n] = z4; }

#pragma unroll 1
  for (int t = 0; t < NSTEP; ++t) {
    const int k0 = t * KT;
    if (k0 >= vmax) break;   // uniform across block

    // ---- stage K, PK tiles (fp32 -> f16, padded rows) ----
#pragma unroll
    for (int i = 0; i < 4; ++i) {
      const int gg = tid + 512 * i;                  // [0, 2048)
      const int d8 = gg & 7, kk = (gg >> 3) & 31, b = gg >> 8;
      const float* src = Kg + ((size_t)(b0 + b) * TKn + (k0 + kk)) * Dn + d8 * 8;
      float4 x = *(const float4*)src, y = *(const float4*)(src + 4);
      char* dst = sm + LK + b * KTILE + kk * KROW + d8 * 16;
      *(f16x4*)dst = cvt4(x);
      *(f16x4*)(dst + 8) = cvt4(y);
    }
#pragma unroll
    for (int i = 0; i < 8; ++i) {
      const int gg = tid + 512 * i;                  // [0, 4096)
      const int d8 = gg & 7, kk = (gg >> 3) & 31, q = gg >> 8;
      const float* src = PKg + ((size_t)(q0 + q) * TKn + (k0 + kk)) * Dn + d8 * 8;
      float4 x = *(const float4*)src, y = *(const float4*)(src + 4);
      char* dst = sm + LPK + q * KTILE + kk * KROW + d8 * 16;
      *(f16x4*)dst = cvt4(x);
      *(f16x4*)(dst + 8) = cvt4(y);
    }
    __syncthreads();

    // ---- scores: content (M=q, per b=w) + pos (M=b, per q=2w,2w+1) ----
    f32x4 Cc[2], Cp[2][2];
#pragma unroll
    for (int n = 0; n < 2; ++n) { Cc[n] = z4; Cp[0][n] = z4; Cp[1][n] = z4; }
#pragma unroll
    for (int c = 0; c < 2; ++c)
#pragma unroll
      for (int n = 0; n < 2; ++n) {
        f16x8 bf = ld8(sm + LK + w * KTILE + (n * 16 + l16) * KROW + c * 64 + g * 16);
        Cc[n] = __builtin_amdgcn_mfma_f32_16x16x32_f16(aQc[c], bf, Cc[n], 0, 0, 0);
      }
#pragma unroll
    for (int qi = 0; qi < 2; ++qi)
#pragma unroll
      for (int c = 0; c < 2; ++c)
#pragma unroll
        for (int n = 0; n < 2; ++n) {
          f16x8 bf = ld8(sm + LPK + (2 * w + qi) * KTILE + (n * 16 + l16) * KROW + c * 64 + g * 16);
          Cp[qi][n] = __builtin_amdgcn_mfma_f32_16x16x32_f16(aQp[qi][c], bf, Cp[qi][n], 0, 0, 0);
        }
    // content scores -> lS   (row combo r = b*16 + q)
#pragma unroll
    for (int n = 0; n < 2; ++n)
#pragma unroll
      for (int r = 0; r < 4; ++r)
        sS[(w * 16 + g * 4 + r) * SROWF + n * 16 + l16] = Cc[n][r];
    __syncthreads();
    // pos scores add (rows 8..15 of padded M are dropped)
#pragma unroll
    for (int qi = 0; qi < 2; ++qi)
#pragma unroll
      for (int n = 0; n < 2; ++n)
#pragma unroll
        for (int r = 0; r < 4; ++r) {
          const int rowb = g * 4 + r;
          if (rowb < 8)
            sS[(rowb * 16 + 2 * w + qi) * SROWF + n * 16 + l16] += Cp[qi][n][r];
        }
    __syncthreads();

    // ---- online softmax (4 threads per row); P f16 aliased over S row bytes [0,64) ----
    {
      const int r = tid >> 2, j4 = tid & 3;
      const float* srow = sS + r * SROWF + j4 * 8;
      const int vl = sVL[r >> 4];
      float v[8];
#pragma unroll
      for (int jj = 0; jj < 8; ++jj) {
        const float s = srow[jj] * 0.125f;
        v[jj] = (k0 + j4 * 8 + jj < vl) ? s : -1.0e6f;
      }
      float mloc = v[0];
#pragma unroll
      for (int jj = 1; jj < 8; ++jj) mloc = fmaxf(mloc, v[jj]);
      mloc = fmaxf(mloc, __shfl_xor(mloc, 1));
      mloc = fmaxf(mloc, __shfl_xor(mloc, 2));
      const float mo = sM[r];
      const float mn = fmaxf(mo, mloc);
      float pv[8], ps = 0.f;
#pragma unroll
      for (int jj = 0; jj < 8; ++jj) { pv[jj] = __expf(v[jj] - mn); ps += pv[jj]; }
      ps += __shfl_xor(ps, 1);
      ps += __shfl_xor(ps, 2);
      if (j4 == 0) {
        const float al = __expf(mo - mn);
        sM[r] = mn; sA[r] = al;
        sL[r] = sL[r] * al + ps;
      }
      f16x4 p0, p1;
#pragma unroll
      for (int jj = 0; jj < 4; ++jj) { p0[jj] = (f16)pv[jj]; p1[jj] = (f16)pv[4 + jj]; }
      // same-wave in-order LDS: all S reads above precede these writes
      *(f16x4*)(sm + LS + r * 136 + j4 * 16) = p0;
      *(f16x4*)(sm + LS + r * 136 + j4 * 16 + 8) = p1;
    }

    // ---- stage V^T, PV^T (transposed f16, padded d-rows; K/PK region is dead now) ----
#pragma unroll
    for (int i = 0; i < 4; ++i) {
      const int p = tid + 512 * i;                   // [0, 2048)
      const int d4 = p & 15, kk2 = (p >> 4) & 15, b = p >> 8;
      const float* src = Vg + ((size_t)(b0 + b) * TKn + (k0 + 2 * kk2)) * Dn + d4 * 4;
      F4 r0, r1; r0.v = *(const float4*)src; r1.v = *(const float4*)(src + Dn);
      char* base = sm + LVT + b * VTILE + kk2 * 4;
#pragma unroll
      for (int j = 0; j < 4; ++j) {
        f16x2 t2; t2[0] = (f16)r0.a[j]; t2[1] = (f16)r1.a[j];
        *(f16x2*)(base + (d4 * 4 + j) * VTROW) = t2;
      }
    }
#pragma unroll
    for (int i = 0; i < 8; ++i) {
      const int p = tid + 512 * i;                   // [0, 4096)
      const int d4 = p & 15, kk2 = (p >> 4) & 15, q = p >> 8;
      const float* src = PVg + ((size_t)(q0 + q) * TKn + (k0 + 2 * kk2)) * Dn + d4 * 4;
      F4 r0, r1; r0.v = *(const float4*)src; r1.v = *(const float4*)(src + Dn);
      char* base = sm + LPVT + q * VTILE + kk2 * 4;
#pragma unroll
      for (int j = 0; j < 4; ++j) {
        f16x2 t2; t2[0] = (f16)r0.a[j]; t2[1] = (f16)r1.a[j];
        *(f16x2*)(base + (d4 * 4 + j) * VTROW) = t2;
      }
    }
    __syncthreads();

    // ---- rescale accumulators by alpha, then O += P*V (content) + P*PV (pos) ----
    {
      float alC[4], alP0[4], alP1[4];
#pragma unroll
      for (int r = 0; r < 4; ++r) {
        alC[r] = sA[w * 16 + g * 4 + r];
        const int rb = (g * 4 + r) & 7;              // rows>=8: value irrelevant (acc stays 0)
        alP0[r] = sA[rb * 16 + 2 * w];
        alP1[r] = sA[rb * 16 + 2 * w + 1];
      }
#pragma unroll
      for (int n = 0; n < 4; ++n)
#pragma unroll
        for (int r = 0; r < 4; ++r) {
          Oc[n][r] *= alC[r];
          Op[0][n][r] *= alP0[r];
          Op[1][n][r] *= alP1[r];
        }
      const f16x8 aPc = ld8(sm + LS + (w * 16 + l16) * 136 + g * 16);
      f16x8 aPp[2];
#pragma unroll
      for (int qi = 0; qi < 2; ++qi) {
        if (l16 < 8) aPp[qi] = ld8(sm + LS + (l16 * 16 + 2 * w + qi) * 136 + g * 16);
        else { f16x8 z = {0, 0, 0, 0, 0, 0, 0, 0}; aPp[qi] = z; }
      }
#pragma unroll
      for (int n = 0; n < 4; ++n) {
        f16x8 bf = ld8(sm + LVT + w * VTILE + (n * 16 + l16) * VTROW + g * 16);
        Oc[n] = __builtin_amdgcn_mfma_f32_16x16x32_f16(aPc, bf, Oc[n], 0, 0, 0);
      }
#pragma unroll
      for (int qi = 0; qi < 2; ++qi)
#pragma unroll
        for (int n = 0; n < 4; ++n) {
          f16x8 bf = ld8(sm + LPVT + (2 * w + qi) * VTILE + (n * 16 + l16) * VTROW + g * 16);
          Op[qi][n] = __builtin_amdgcn_mfma_f32_16x16x32_f16(aPp[qi], bf, Op[qi][n], 0, 0, 0);
        }
    }
    __syncthreads();
  }

  // ---- epilogue: combine pos O (rows=b) into content O (rows=q) via LDS, normalize, store ----
  float* const sO = (float*)(sm + LVT);   // ops region is free now
#pragma unroll
  for (int qi = 0; qi < 2; ++qi)
#pragma unroll
    for (int n = 0; n < 4; ++n)
#pragma unroll
      for (int r = 0; r < 4; ++r) {
        const int rowb = g * 4 + r;
        if (rowb < 8)
          sO[(rowb * 16 + 2 * w + qi) * OROWF + n * 16 + l16] = Op[qi][n][r];
      }
  __syncthreads();
#pragma unroll
  for (int n = 0; n < 4; ++n)
#pragma unroll
    for (int r = 0; r < 4; ++r) {
      const int q = g * 4 + r;
      const int rr = w * 16 + q;
      const float val = (Oc[n][r] + sO[rr * OROWF + n * 16 + l16]) / sL[rr];
      Og[((size_t)(b0 + w) * TQn + (q0 + q)) * Dn + n * 16 + l16] = val;
    }
}

extern "C" void kernel_launch(void* const* d_in, const int* in_sizes, int n_in,
                              void* d_out, int out_size, void* d_ws, size_t ws_size,
                              hipStream_t stream) {
  (void)in_sizes; (void)n_in; (void)out_size; (void)d_ws; (void)ws_size;
  const float* Qg  = (const float*)d_in[0];
  const float* Kg  = (const float*)d_in[1];
  const float* Vg  = (const float*)d_in[2];
  const float* PKg = (const float*)d_in[3];
  const float* PVg = (const float*)d_in[4];
  const int*   VLg = (const int*)d_in[5];
  float* Og = (float*)d_out;

  dim3 grid(TQn / NQ, Bn / NB, 1);   // 64 x 4 = 256 blocks, 1/CU
  dim3 block(512, 1, 1);
  hipLaunchKernelGGL(attn_rpr_mfma, grid, block, 0, stream, Qg, Kg, Vg, PKg, PVg, VLg, Og);
}

// Round 2
// 803.556 us; speedup vs baseline: 1.8137x; 1.1007x over previous
//
#include <hip/hip_runtime.h>

typedef _Float16 f16;
typedef _Float16 f16x2 __attribute__((ext_vector_type(2)));
typedef _Float16 f16x4 __attribute__((ext_vector_type(4)));
typedef _Float16 f16x8 __attribute__((ext_vector_type(8)));
typedef float f32x4 __attribute__((ext_vector_type(4)));

constexpr int TQn = 1024, TKn = 1024, Dn = 64, Bn = 32;
constexpr int NB = 16;            // batches per block
constexpr int NQ = 32;            // queries per block
constexpr int KT = 16;            // k-tile
constexpr int NSPLIT = 4;         // k-split factor
constexpr int KRANGE = TKn / NSPLIT;   // 256
constexpr int NSTEP = KRANGE / KT;     // 16

// ---- LDS byte layout ----
constexpr int KROW  = 136;                 // 64 f16 + 4 pad (8B-aligned rows)
constexpr int KTILE = KT * KROW;           // 2176 per b (or q)
constexpr int LK    = 0;                   // K:  16*2176 = 34816
constexpr int LPK   = NB * KTILE;          // PK: 32*2176 = 69632 (end 104448)
constexpr int VTROW = 36;                  // 16 f16 + 2 pad (4B-aligned rows)
constexpr int VTILE = Dn * VTROW;          // 2304 per b (or q)
constexpr int LVT   = 0;                   // V^T:  16*2304 = 36864 (aliases K)
constexpr int LPVT  = NB * VTILE;          // PV^T: 32*2304 = 73728 (end 110592)
constexpr int OPSEND = 110592;
constexpr int LS    = OPSEND;              // S: 512 rows x 72B (16 f32 + pad; P f16 aliased in-row)
constexpr int SSTR  = 72;
constexpr int LAo   = LS + 512 * SSTR;     // 147456: per-step alpha, 512 f32
constexpr int SMEMB = LAo + 2048;          // 149504 B -> 1 block/CU

union F4 { float4 v; float a[4]; };

__device__ __forceinline__ f16x8 ld8(const void* p) {   // 8B-aligned f16x8 (2x b64)
  f16x4 a = *(const f16x4*)p;
  f16x4 b = *(const f16x4*)((const char*)p + 8);
  return __builtin_shufflevector(a, b, 0, 1, 2, 3, 4, 5, 6, 7);
}
__device__ __forceinline__ f16x4 ld4u(const void* p) {  // 4B-aligned f16x4 (2x b32)
  union { uint u[2]; f16x4 h; } x;
  x.u[0] = *(const uint*)p; x.u[1] = *(const uint*)((const char*)p + 4);
  return x.h;
}
__device__ __forceinline__ f16x4 cvt4(float4 x) {
  f16x4 r; r[0] = (f16)x.x; r[1] = (f16)x.y; r[2] = (f16)x.z; r[3] = (f16)x.w;
  return r;
}

// Wave w (0..7): content b-pair {2w, 2w+1}; pos q-quad {4w..4w+3}.
// S row index r = b_loc*32 + q_loc. 16x16 MFMA C/D: col=lane&15, row=(lane>>4)*4+reg.
__global__ __launch_bounds__(512, 2)
void attn_fwd(const float* __restrict__ Qg, const float* __restrict__ Kg,
              const float* __restrict__ Vg, const float* __restrict__ PKg,
              const float* __restrict__ PVg, const int* __restrict__ VLg,
              float* __restrict__ Ows, float* __restrict__ Mws, float* __restrict__ Lws) {
  __shared__ __align__(16) char sm[SMEMB];
  float* const sS = (float*)(sm + LS);
  float* const sA = (float*)(sm + LAo);

  const int tid = (int)threadIdx.x;
  const int w = tid >> 6;
  const int l = tid & 63;
  const int l16 = l & 15, g = l >> 4;
  const int qt = (int)blockIdx.x, bg = (int)blockIdx.y, ks = (int)blockIdx.z;
  const int q0 = qt * NQ, b0 = bg * NB;
  const int kbase = ks * KRANGE;

  // ---- persistent Q fragments (f16) ----
  f16x8 aC[2][2][2];   // [i][mt][c2] : content, A rows = q
  f16x8 aP[4][2];      // [qq][c2]    : pos,     A rows = b
#pragma unroll
  for (int i = 0; i < 2; ++i)
#pragma unroll
    for (int mt = 0; mt < 2; ++mt) {
      const float* qr = Qg + ((size_t)(b0 + 2 * w + i) * TQn + (q0 + mt * 16 + l16)) * Dn;
#pragma unroll
      for (int c = 0; c < 2; ++c) {
        float4 x = *(const float4*)(qr + c * 32 + g * 8);
        float4 y = *(const float4*)(qr + c * 32 + g * 8 + 4);
        aC[i][mt][c] = __builtin_shufflevector(cvt4(x), cvt4(y), 0, 1, 2, 3, 4, 5, 6, 7);
      }
    }
#pragma unroll
  for (int qq = 0; qq < 4; ++qq) {
    const float* qr = Qg + ((size_t)(b0 + l16) * TQn + (q0 + 4 * w + qq)) * Dn;
#pragma unroll
    for (int c = 0; c < 2; ++c) {
      float4 x = *(const float4*)(qr + c * 32 + g * 8);
      float4 y = *(const float4*)(qr + c * 32 + g * 8 + 4);
      aP[qq][c] = __builtin_shufflevector(cvt4(x), cvt4(y), 0, 1, 2, 3, 4, 5, 6, 7);
    }
  }

  int vmax = 0;
#pragma unroll
  for (int i = 0; i < NB; ++i) vmax = max(vmax, VLg[b0 + i]);
  const int vl_row = VLg[b0 + (tid >> 5)];   // softmax row r=tid -> b = r>>5

  // ---- staging per-thread constants ----
  const int d4 = tid & 15, kc = (tid >> 4) & 15, bb = tid >> 8;         // K/PK pattern
  const float* Kt  = Kg  + ((size_t)(b0 + bb) * TKn + kc) * Dn + d4 * 4;
  const float* PKt = PKg + ((size_t)(q0 + bb) * TKn + kc) * Dn + d4 * 4;
  char* const dK  = sm + LK  + bb * KTILE + kc * KROW + d4 * 8;
  char* const dPK = sm + LPK + bb * KTILE + kc * KROW + d4 * 8;
  const int k2 = tid & 7, dv = (tid >> 3) & 15, bv = tid >> 7;          // V/PV pattern
  const float* Vt  = Vg  + ((size_t)(b0 + bv) * TKn + 2 * k2) * Dn + dv * 4;
  const float* PVt = PVg + ((size_t)(q0 + bv) * TKn + 2 * k2) * Dn + dv * 4;
  char* const dV  = sm + LVT  + bv * VTILE + k2 * 4;
  char* const dPV = sm + LPVT + bv * VTILE + k2 * 4;

  const f32x4 z4 = {0.f, 0.f, 0.f, 0.f};
  f32x4 Oc[2][2][4], Op[4][4];
#pragma unroll
  for (int n = 0; n < 4; ++n) {
#pragma unroll
    for (int i = 0; i < 2; ++i) { Oc[i][0][n] = z4; Oc[i][1][n] = z4; }
#pragma unroll
    for (int qq = 0; qq < 4; ++qq) Op[qq][n] = z4;
  }
  float m_run = -3.0e38f, l_run = 0.0f;   // softmax state for row r = tid

  __syncthreads();

#pragma unroll 1
  for (int t = 0; t < NSTEP; ++t) {
    const int k0 = kbase + t * KT;
    if (k0 >= vmax) break;   // uniform across block
    const int kof = k0 * Dn;

    // ---- stage K (8 quads) + PK (16 quads), fp32 -> f16 ----
#pragma unroll
    for (int i = 0; i < 8; ++i) {
      float4 v = *(const float4*)(Kt + kof + i * 131072);       // b += 2 per i
      *(f16x4*)(dK + i * (2 * KTILE)) = cvt4(v);
    }
#pragma unroll
    for (int i = 0; i < 16; ++i) {
      float4 v = *(const float4*)(PKt + kof + i * 131072);      // q += 2 per i
      *(f16x4*)(dPK + i * (2 * KTILE)) = cvt4(v);
    }
    __syncthreads();

    // ---- scores: content (write S) + pos (hold, add after barrier) ----
    f32x4 Cp[4];
#pragma unroll
    for (int qq = 0; qq < 4; ++qq) Cp[qq] = z4;
#pragma unroll
    for (int i = 0; i < 2; ++i) {
      const f16x8 bf0 = ld8(sm + LK + (2 * w + i) * KTILE + l16 * KROW + g * 16);
      const f16x8 bf1 = ld8(sm + LK + (2 * w + i) * KTILE + l16 * KROW + 64 + g * 16);
#pragma unroll
      for (int mt = 0; mt < 2; ++mt) {
        f32x4 acc = z4;
        acc = __builtin_amdgcn_mfma_f32_16x16x32_f16(aC[i][mt][0], bf0, acc, 0, 0, 0);
        acc = __builtin_amdgcn_mfma_f32_16x16x32_f16(aC[i][mt][1], bf1, acc, 0, 0, 0);
#pragma unroll
        for (int rr = 0; rr < 4; ++rr)
          sS[((2 * w + i) * 32 + mt * 16 + g * 4 + rr) * (SSTR / 4) + l16] = acc[rr];
      }
    }
#pragma unroll
    for (int qq = 0; qq < 4; ++qq) {
      const f16x8 bf0 = ld8(sm + LPK + (4 * w + qq) * KTILE + l16 * KROW + g * 16);
      const f16x8 bf1 = ld8(sm + LPK + (4 * w + qq) * KTILE + l16 * KROW + 64 + g * 16);
      Cp[qq] = __builtin_amdgcn_mfma_f32_16x16x32_f16(aP[qq][0], bf0, Cp[qq], 0, 0, 0);
      Cp[qq] = __builtin_amdgcn_mfma_f32_16x16x32_f16(aP[qq][1], bf1, Cp[qq], 0, 0, 0);
    }
    __syncthreads();

    // ---- pos add into S; stage V^T + PV^T (K/PK region now dead) ----
#pragma unroll
    for (int qq = 0; qq < 4; ++qq)
#pragma unroll
      for (int rr = 0; rr < 4; ++rr)
        sS[((g * 4 + rr) * 32 + 4 * w + qq) * (SSTR / 4) + l16] += Cp[qq][rr];
#pragma unroll
    for (int i = 0; i < 4; ++i) {
      F4 r0, r1;
      r0.v = *(const float4*)(Vt + kof + i * 262144);           // b += 4 per i
      r1.v = *(const float4*)(Vt + kof + i * 262144 + Dn);
      char* base = dV + i * (4 * VTILE);
#pragma unroll
      for (int j = 0; j < 4; ++j) {
        f16x2 t2; t2[0] = (f16)r0.a[j]; t2[1] = (f16)r1.a[j];
        *(f16x2*)(base + (dv * 4 + j) * VTROW) = t2;
      }
    }
#pragma unroll
    for (int i = 0; i < 8; ++i) {
      F4 r0, r1;
      r0.v = *(const float4*)(PVt + kof + i * 262144);          // q += 4 per i
      r1.v = *(const float4*)(PVt + kof + i * 262144 + Dn);
      char* base = dPV + i * (4 * VTILE);
#pragma unroll
      for (int j = 0; j < 4; ++j) {
        f16x2 t2; t2[0] = (f16)r0.a[j]; t2[1] = (f16)r1.a[j];
        *(f16x2*)(base + (dv * 4 + j) * VTROW) = t2;
      }
    }
    __syncthreads();

    // ---- online softmax: one thread per row; P f16 aliased over row bytes [0,32) ----
    {
      float* row = sS + tid * (SSTR / 4);
      float v[16]; float mloc = -3.0e38f;
#pragma unroll
      for (int j = 0; j < 16; ++j) {
        const float s = row[j] * 0.125f;
        v[j] = (k0 + j < vl_row) ? s : -1.0e6f;
        mloc = fmaxf(mloc, v[j]);
      }
      const float mn = fmaxf(m_run, mloc);
      float ps = 0.f; f16 ph[16];
#pragma unroll
      for (int j = 0; j < 16; ++j) { const float p = __expf(v[j] - mn); ps += p; ph[j] = (f16)p; }
      const float al = __expf(m_run - mn);
      m_run = mn; l_run = l_run * al + ps;
      sA[tid] = al;
#pragma unroll
      for (int j = 0; j < 4; ++j) {
        f16x4 pk; pk[0] = ph[4 * j]; pk[1] = ph[4 * j + 1]; pk[2] = ph[4 * j + 2]; pk[3] = ph[4 * j + 3];
        *(f16x4*)((char*)row + j * 8) = pk;
      }
    }
    __syncthreads();

    // ---- O += P*(V) and P*(PV): rescale by alpha, then K=16 MFMAs ----
    {
#pragma unroll
      for (int i = 0; i < 2; ++i)
#pragma unroll
        for (int mt = 0; mt < 2; ++mt)
#pragma unroll
          for (int rr = 0; rr < 4; ++rr) {
            const float al = sA[(2 * w + i) * 32 + mt * 16 + g * 4 + rr];
#pragma unroll
            for (int n = 0; n < 4; ++n) Oc[i][mt][n][rr] *= al;
          }
#pragma unroll
      for (int qq = 0; qq < 4; ++qq)
#pragma unroll
        for (int rr = 0; rr < 4; ++rr) {
          const float al = sA[(g * 4 + rr) * 32 + 4 * w + qq];
#pragma unroll
          for (int n = 0; n < 4; ++n) Op[qq][n][rr] *= al;
        }
#pragma unroll
      for (int i = 0; i < 2; ++i) {
        f16x4 pa[2];
#pragma unroll
        for (int mt = 0; mt < 2; ++mt)
          pa[mt] = *(const f16x4*)(sm + LS + ((2 * w + i) * 32 + mt * 16 + l16) * SSTR + g * 8);
#pragma unroll
        for (int n = 0; n < 4; ++n) {
          const f16x4 bf = ld4u(sm + LVT + (2 * w + i) * VTILE + (n * 16 + l16) * VTROW + g * 8);
#pragma unroll
          for (int mt = 0; mt < 2; ++mt)
            Oc[i][mt][n] = __builtin_amdgcn_mfma_f32_16x16x16f16(pa[mt], bf, Oc[i][mt][n], 0, 0, 0);
        }
      }
#pragma unroll
      for (int qq = 0; qq < 4; ++qq) {
        const f16x4 pa = *(const f16x4*)(sm + LS + (l16 * 32 + 4 * w + qq) * SSTR + g * 8);
#pragma unroll
        for (int n = 0; n < 4; ++n) {
          const f16x4 bf = ld4u(sm + LPVT + (4 * w + qq) * VTILE + (n * 16 + l16) * VTROW + g * 8);
          Op[qq][n] = __builtin_amdgcn_mfma_f32_16x16x16f16(pa, bf, Op[qq][n], 0, 0, 0);
        }
      }
    }
    __syncthreads();
  }

  // ---- epilogue: merge pos O (rows=b) into content O (rows=q) via LDS, write partials ----
  float* const sO = (float*)sm;   // 512 rows x 68 f32 (272B) = 139264 B, fits below sA
#pragma unroll
  for (int qq = 0; qq < 4; ++qq)
#pragma unroll
    for (int n = 0; n < 4; ++n)
#pragma unroll
      for (int rr = 0; rr < 4; ++rr)
        sO[((g * 4 + rr) * 32 + 4 * w + qq) * 68 + n * 16 + l16] = Op[qq][n][rr];
  __syncthreads();
#pragma unroll
  for (int i = 0; i < 2; ++i)
#pragma unroll
    for (int mt = 0; mt < 2; ++mt)
#pragma unroll
      for (int rr = 0; rr < 4; ++rr) {
        const int rloc = (2 * w + i) * 32 + mt * 16 + g * 4 + rr;
        float* dst = Ows + (((size_t)ks * Bn + (b0 + 2 * w + i)) * TQn + (q0 + mt * 16 + g * 4 + rr)) * Dn;
#pragma unroll
        for (int n = 0; n < 4; ++n)
          dst[n * 16 + l16] = Oc[i][mt][n][rr] + sO[rloc * 68 + n * 16 + l16];
      }
  {
    const size_t idx = ((size_t)ks * Bn + (b0 + (tid >> 5))) * TQn + (q0 + (tid & 31));
    Mws[idx] = m_run; Lws[idx] = l_run;
  }
}

// ---- combine the 4 k-split partials ----
__global__ __launch_bounds__(256)
void combine4(const float* __restrict__ Ows, const float* __restrict__ Mws,
              const float* __restrict__ Lws, float* __restrict__ Og) {
  const int gid = (int)blockIdx.x * 256 + (int)threadIdx.x;
  const int d = gid & 63;
  const int row = gid >> 6;                 // b*1024 + q
  float m[NSPLIT], lv[NSPLIT];
#pragma unroll
  for (int s = 0; s < NSPLIT; ++s) { m[s] = Mws[s * 32768 + row]; lv[s] = Lws[s * 32768 + row]; }
  float M = fmaxf(fmaxf(m[0], m[1]), fmaxf(m[2], m[3]));
  float L = 0.f, o = 0.f;
#pragma unroll
  for (int s = 0; s < NSPLIT; ++s) {
    const float wgt = __expf(m[s] - M);     // fully-masked splits underflow to 0
    L += wgt * lv[s];
    o += wgt * Ows[((size_t)s * 32768 + row) * 64 + d];
  }
  Og[(size_t)row * 64 + d] = o / L;
}

extern "C" void kernel_launch(void* const* d_in, const int* in_sizes, int n_in,
                              void* d_out, int out_size, void* d_ws, size_t ws_size,
                              hipStream_t stream) {
  (void)in_sizes; (void)n_in; (void)out_size; (void)ws_size;
  const float* Qg  = (const float*)d_in[0];
  const float* Kg  = (const float*)d_in[1];
  const float* Vg  = (const float*)d_in[2];
  const float* PKg = (const float*)d_in[3];
  const float* PVg = (const float*)d_in[4];
  const int*   VLg = (const int*)d_in[5];
  float* Og = (float*)d_out;

  float* ws  = (float*)d_ws;
  float* Ows = ws;                          // 4 * 32 * 1024 * 64 f32 = 32 MiB
  float* Mws = ws + 8388608;                // 4 * 32768 f32
  float* Lws = ws + 8519680;                // 4 * 32768 f32  (total ws: 34,603,008 B)

  dim3 grid(TQn / NQ, Bn / NB, NSPLIT);     // 32 x 2 x 4 = 256 blocks, 1/CU
  dim3 block(512, 1, 1);
  hipLaunchKernelGGL(attn_fwd, grid, block, 0, stream, Qg, Kg, Vg, PKg, PVg, VLg, Ows, Mws, Lws);

  dim3 cgrid((Bn * TQn * Dn) / 256, 1, 1);  // 8192 blocks
  dim3 cblock(256, 1, 1);
  hipLaunchKernelGGL(combine4, cgrid, cblock, 0, stream, Ows, Mws, Lws, Og);
}